// Round 18
// baseline (678.603 us; speedup 1.0000x reference)
//
#include <hip/hip_runtime.h>
#include <hip/hip_bf16.h>

#define BB 2
#define SS 112
#define HH 768
#define MM 256
#define LL 54
#define OO 10
#define NPAIR (BB*SS*SS)          // 25088
#define NQPOS (BB*SS*SS*SS)       // 2809856
#define SO (SS*OO)                // 1120
#define SOP 1152                  // padded row count for vU area
#define S2 (SS*SS)                // 12544
#define NQBLK (NQPOS/512)         // 5488
#define NJBLK (NPAIR/128)         // 196 jointg blocks (CE partials)
#define NHEAVY (NJBLK + 9*98*BB)  // 1960

typedef short bf16x8 __attribute__((ext_vector_type(8)));
typedef float f32x4 __attribute__((ext_vector_type(4)));

// workspace layout (float units)
#define WS_CNT   0                // 1 uint: qloss completion counter
#define WS_HP    64
#define WS_TP    57408
#define WS_VAL   114752
#define WS_UT    172096
#define WS_VUB   827456          // bf16 area: BB*SOP*MM bf16
#define WS_PAIRB 1122368         // bf16 area: NPAIR*MM bf16
#define WS_FWB   4333632         // bf16 area: 64*MM bf16
#define WS_QPART 4341824         // 2*NQBLK floats
#define WS_EPART 4352800         // 2*NJBLK floats

__device__ __forceinline__ float gelu_exact(float v) {
    return 0.5f * v * (1.0f + erff(v * 0.70710678118654752f));
}

// ---- 1. k_pre: proj (672) | transU (640) | prepB (64) ----------------------
__global__ __launch_bounds__(256) void k_pre(const float* __restrict__ x,
                                             const float* __restrict__ pw,
                                             const float* __restrict__ vw,
                                             const float* __restrict__ vb,
                                             const float* __restrict__ U,
                                             const float* __restrict__ fw,
                                             float* __restrict__ hp,
                                             float* __restrict__ tp,
                                             float* __restrict__ val,
                                             float* __restrict__ UT,
                                             __hip_bfloat16* __restrict__ fwb) {
    __shared__ float sm[1056];                  // max(768, 32*33)
    const int id = blockIdx.x;
    const int tid = threadIdx.x;
    if (id < 672) {
        const int row = id % 224, sel = id / 224;
        const float* xr = x + (long)row * HH;
        for (int i = tid; i < HH; i += 256) sm[i] = xr[i];
        __syncthreads();
        const int m = tid;
        const float* w = (sel == 0) ? pw : (sel == 1) ? (pw + (long)HH * MM) : vw;
        float a = 0.f;
        for (int h = 0; h < HH; ++h)
            a = fmaf(sm[h], w[(long)h * MM + m], a);
        if (sel == 0)      hp[(long)row * MM + m] = a;
        else if (sel == 1) tp[(long)row * MM + m] = a;
        else               val[(long)row * MM + m] = gelu_exact(a + vb[m]);
    } else if (id < 1312) {
        const int t = id - 672;
        const int o = t / 64, rest = t % 64;
        const int i0 = (rest >> 3) * 32, j0 = (rest & 7) * 32;
        const int tx = tid & 31, ty = tid >> 5;  // 32 x 8
        float (*tt)[33] = (float(*)[33])sm;
        for (int r = 0; r < 32; r += 8)
            tt[ty + r][tx] = U[((long)(o * MM + i0 + ty + r)) * MM + j0 + tx];
        __syncthreads();
        for (int r = 0; r < 32; r += 8)
            UT[((long)(o * MM + j0 + ty + r)) * MM + i0 + tx] = tt[tx][ty + r];
    } else {
        const int idx2 = (id - 1312) * 256 + tid;   // 0..16383
        const int c = idx2 >> 8, k = idx2 & 255;
        const float v = (c < LL) ? fw[(long)k * LL + c] : 0.f;
        fwb[idx2] = __float2bfloat16(v);
    }
}

// ---- 2. k_mid: vU (280) | pair (448) ---------------------------------------
__global__ __launch_bounds__(256) void k_mid(const float* __restrict__ val,
                                             const float* __restrict__ UT,
                                             __hip_bfloat16* __restrict__ vub,
                                             const float* __restrict__ hp,
                                             const float* __restrict__ tp,
                                             const float* __restrict__ pb,
                                             __hip_bfloat16* __restrict__ pairb) {
    __shared__ float sm[8 * MM];                // 8 KB
    const int id = blockIdx.x;
    const int tid = threadIdx.x;
    if (id < 280) {
        const int b = id / 140, r = id % 140;
        const int o = r / 14, zt = r % 14;
        const int z0 = zt * 8;
        float (*vs)[MM] = (float(*)[MM])sm;
        for (int idx = tid; idx < 8 * MM; idx += 256) {
            const int zz = idx >> 8, m = idx & 255;
            vs[zz][m] = val[((long)(b * SS + z0 + zz)) * MM + m];
        }
        __syncthreads();
        const int i = tid;
        float acc[8];
#pragma unroll
        for (int zz = 0; zz < 8; ++zz) acc[zz] = 0.f;
        const float* utp = UT + (long)o * MM * MM + i;
        for (int j = 0; j < MM; ++j) {
            const float u = utp[(long)j * MM];
#pragma unroll
            for (int zz = 0; zz < 8; ++zz) acc[zz] = fmaf(vs[zz][j], u, acc[zz]);
        }
#pragma unroll
        for (int zz = 0; zz < 8; ++zz)
            vub[((long)b * SOP + (z0 + zz) * OO + o) * MM + i] = __float2bfloat16(acc[zz]);
    } else {
        const int p = id - 280;                 // 0..447
        const int bx = p % 224;
        const int y0base = (p / 224) * 56;
        sm[tid] = hp[(long)bx * MM + tid] + pb[tid];
        __syncthreads();
        const int b = bx / SS;
        const int half = tid >> 7;
        const int m0 = (tid & 127) * 2;
        const float h0 = sm[m0], h1 = sm[m0 + 1];
        for (int y0 = y0base; y0 < y0base + 56; y0 += 2) {
            const int y = y0 + half;
            const float2 t2 = *(const float2*)(tp + ((long)(b * SS + y)) * MM + m0);
            __hip_bfloat162 o2;
            o2.x = __float2bfloat16(gelu_exact(h0 + t2.x));
            o2.y = __float2bfloat16(gelu_exact(h1 + t2.y));
            *(__hip_bfloat162*)(pairb + ((long)bx * SS + y) * MM + m0) = o2;
        }
    }
}

// ---- block reduce -> per-block partial (no atomics) ------------------------
__device__ __forceinline__ void reduce2_part(float v1, float v2, float* slot) {
    const int lane = threadIdx.x & 63, wid = threadIdx.x >> 6;
#pragma unroll
    for (int off = 32; off > 0; off >>= 1) {
        v1 += __shfl_down(v1, off, 64);
        v2 += __shfl_down(v2, off, 64);
    }
    __shared__ float w1[4], w2[4];
    if (lane == 0) { w1[wid] = v1; w2[wid] = v2; }
    __syncthreads();
    if (threadIdx.x == 0) {
        slot[0] = w1[0] + w1[1] + w1[2] + w1[3];
        slot[1] = w2[0] + w2[1] + w2[2] + w2[3];
    }
}

// ---- 3. k_heavy: jointg+CE (196) | qgemm (1764) ----------------------------
__global__ __launch_bounds__(256) void k_heavy(const __hip_bfloat16* __restrict__ pairb,
                                               const __hip_bfloat16* __restrict__ fwb,
                                               const float* __restrict__ fb,
                                               const int* __restrict__ jlab,
                                               const int* __restrict__ jmask,
                                               float* __restrict__ joint,
                                               float* __restrict__ epart,
                                               const __hip_bfloat16* __restrict__ vub,
                                               float* __restrict__ qout) {
    __shared__ __align__(16) char smem[32768];
    char* Al = smem;
    const int id = blockIdx.x;
    const int tid = threadIdx.x;
    const int lane = tid & 63, wid = tid >> 6;
    const int rl = lane & 15, kb = lane >> 4;

    if (id < NJBLK) {
        // ================= jointg + element-CE =================
        char* Bl = smem + 16384;                // B tile 64x64
        const int r0 = id * 128;

        int arow[4], aci[4], wadA[4];
#pragma unroll
        for (int j = 0; j < 4; ++j) {
            const int chunk = tid + 256 * j;
            arow[j] = chunk >> 3; aci[j] = chunk & 7;
            wadA[j] = (arow[j] * 128 + aci[j] * 16) ^ ((arow[j] & 7) << 4);
        }
        int brow[2], bci[2], wadB[2];
#pragma unroll
        for (int j = 0; j < 2; ++j) {
            const int chunk = tid + 256 * j;
            brow[j] = chunk >> 3; bci[j] = chunk & 7;
            wadB[j] = (brow[j] * 128 + bci[j] * 16) ^ ((brow[j] & 7) << 4);
        }

        f32x4 acc[2][4] = {};
        float4 ra[4], rb[2];

        auto issue = [&](int kt) {
#pragma unroll
            for (int j = 0; j < 4; ++j)
                ra[j] = *(const float4*)((const char*)pairb +
                         ((long)(r0 + arow[j]) * MM + kt * 64 + aci[j] * 8) * 2);
#pragma unroll
            for (int j = 0; j < 2; ++j)
                rb[j] = *(const float4*)((const char*)fwb +
                         ((long)brow[j] * MM + kt * 64 + bci[j] * 8) * 2);
        };
        auto dowrite = [&]() {
#pragma unroll
            for (int j = 0; j < 4; ++j) *(float4*)(Al + wadA[j]) = ra[j];
#pragma unroll
            for (int j = 0; j < 2; ++j) *(float4*)(Bl + wadB[j]) = rb[j];
        };
        auto compute = [&]() {
#pragma unroll
            for (int ks = 0; ks < 2; ++ks) {
                bf16x8 af[2], bv[4];
#pragma unroll
                for (int m = 0; m < 2; ++m) {
                    const int rr = wid * 32 + m * 16 + rl;
                    af[m] = *(const bf16x8*)(Al + ((rr * 128 + ks * 64 + kb * 16) ^ ((rr & 7) << 4)));
                }
#pragma unroll
                for (int n = 0; n < 4; ++n) {
                    const int cc = n * 16 + rl;
                    bv[n] = *(const bf16x8*)(Bl + ((cc * 128 + ks * 64 + kb * 16) ^ ((cc & 7) << 4)));
                }
#pragma unroll
                for (int m = 0; m < 2; ++m)
#pragma unroll
                    for (int n = 0; n < 4; ++n)
                        acc[m][n] = __builtin_amdgcn_mfma_f32_16x16x32_bf16(af[m], bv[n], acc[m][n], 0, 0, 0);
            }
        };

        issue(0); dowrite(); __syncthreads();
        for (int kt = 0; kt < 4; ++kt) {
            if (kt < 3) issue(kt + 1);
            compute();
            __syncthreads();
            if (kt < 3) { dowrite(); __syncthreads(); }
        }

        // epilogue: write joint + stage (with bias) to LDS (stride 55) for CE
        float* stage = (float*)smem;
        __syncthreads();
#pragma unroll
        for (int m = 0; m < 2; ++m)
#pragma unroll
            for (int n = 0; n < 4; ++n) {
                const int col = n * 16 + rl;
                if (col < LL) {
                    const float bias = fb[col];
                    const int lrow0 = wid * 32 + m * 16 + kb * 4;
#pragma unroll
                    for (int j = 0; j < 4; ++j) {
                        const float v = acc[m][n][j] + bias;
                        joint[(long)(r0 + lrow0 + j) * LL + col] = v;
                        stage[(lrow0 + j) * 55 + col] = v;
                    }
                }
            }
        __syncthreads();

        float nll = 0.f, cnt = 0.f;
        if (tid < 128) {
            const int gi = r0 + tid;
            if (jmask[gi] != 0) {
                const float* s = stage + tid * 55;
                float mx = -3.4e38f;
                for (int l = 0; l < LL; ++l) mx = fmaxf(mx, s[l]);
                float se = 0.f;
                for (int l = 0; l < LL; ++l) se += expf(s[l] - mx);
                nll = mx + logf(se) - s[jlab[gi]];
                cnt = 1.f;
            }
        }
        reduce2_part(nll, cnt, epart + 2 * id);
    } else {
        // ================= q_score GEMM 128x128 =================
        char* Bl = smem + 16384;
        const int qid = id - NJBLK;
        const int c0 = (qid % 9) * 128;
        const int r0 = ((qid / 9) % 98) * 128;
        const int b = qid / (9 * 98);
        const __hip_bfloat16* A  = pairb + (long)b * S2 * MM;
        const __hip_bfloat16* Bm = vub + (long)b * SOP * MM;
        const int wr = wid >> 1, wc = wid & 1;

        int arow[4], aci[4], wad[4];
#pragma unroll
        for (int j = 0; j < 4; ++j) {
            const int chunk = tid + 256 * j;
            arow[j] = chunk >> 3; aci[j] = chunk & 7;
            wad[j] = (arow[j] * 128 + aci[j] * 16) ^ ((arow[j] & 7) << 4);
        }

        f32x4 acc[4][4] = {};
        float4 ra[4], rb[4];

        auto issue = [&](int kt) {
#pragma unroll
            for (int j = 0; j < 4; ++j) {
                ra[j] = *(const float4*)((const char*)A +
                         ((long)(r0 + arow[j]) * MM + kt * 64 + aci[j] * 8) * 2);
                rb[j] = *(const float4*)((const char*)Bm +
                         ((long)(c0 + arow[j]) * MM + kt * 64 + aci[j] * 8) * 2);
            }
        };
        auto dowrite = [&]() {
#pragma unroll
            for (int j = 0; j < 4; ++j) {
                *(float4*)(Al + wad[j]) = ra[j];
                *(float4*)(Bl + wad[j]) = rb[j];
            }
        };
        auto compute = [&]() {
#pragma unroll
            for (int ks = 0; ks < 2; ++ks) {
                bf16x8 af[4], bv[4];
#pragma unroll
                for (int m = 0; m < 4; ++m) {
                    const int rr = wr * 64 + m * 16 + rl;
                    af[m] = *(const bf16x8*)(Al + ((rr * 128 + ks * 64 + kb * 16) ^ ((rr & 7) << 4)));
                }
#pragma unroll
                for (int n = 0; n < 4; ++n) {
                    const int cc = wc * 64 + n * 16 + rl;
                    bv[n] = *(const bf16x8*)(Bl + ((cc * 128 + ks * 64 + kb * 16) ^ ((cc & 7) << 4)));
                }
#pragma unroll
                for (int m = 0; m < 4; ++m)
#pragma unroll
                    for (int n = 0; n < 4; ++n)
                        acc[m][n] = __builtin_amdgcn_mfma_f32_16x16x32_bf16(af[m], bv[n], acc[m][n], 0, 0, 0);
            }
        };

        issue(0); dowrite(); __syncthreads();
        for (int kt = 0; kt < 4; ++kt) {
            if (kt < 3) issue(kt + 1);
            compute();
            __syncthreads();
            if (kt < 3) { dowrite(); __syncthreads(); }
        }

        float* C = qout + (long)b * S2 * SO;
#pragma unroll
        for (int m = 0; m < 4; ++m)
#pragma unroll
            for (int n = 0; n < 4; ++n) {
                const int col = c0 + wc * 64 + n * 16 + rl;
                if (col < SO) {
                    const int rbase = r0 + wr * 64 + m * 16 + kb * 4;
#pragma unroll
                    for (int j = 0; j < 4; ++j)
                        C[(long)(rbase + j) * SO + col] = acc[m][n][j];
                }
            }
    }
}

// ---- 4. q loss (LDS-staged, pad-11, partials) + fused final ----------------
__global__ __launch_bounds__(256) void k_qloss(const float* __restrict__ q,
                                               const int* __restrict__ labels,
                                               const int* __restrict__ mask,
                                               float* __restrict__ qpart,
                                               const float* __restrict__ epart,
                                               float* __restrict__ out,
                                               unsigned* __restrict__ cnt_dev) {
    __shared__ float qs[512 * 11];             // 22528 B, stride-11 pad
    const int base = blockIdx.x * 512;
    const float* src = q + (long)base * OO;
    for (int i = threadIdx.x; i < 512 * OO; i += 256) {
        const int p = i / 10, o = i - p * 10;
        qs[p * 11 + o] = src[i];
    }
    __syncthreads();
    float nll = 0.f, cnt = 0.f;
#pragma unroll
    for (int j = 0; j < 2; ++j) {
        const int p = threadIdx.x + 256 * j;
        const int gi = base + p;
        if (mask[gi] != 0) {
            const float* s = qs + p * 11;
            float r[OO];
#pragma unroll
            for (int o = 0; o < OO; ++o) r[o] = s[o];
            float mx = r[0];
#pragma unroll
            for (int o = 1; o < OO; ++o) mx = fmaxf(mx, r[o]);
            float se = 0.f;
#pragma unroll
            for (int o = 0; o < OO; ++o) { r[o] = expf(r[o] - mx); se += r[o]; }
            const float inv = 1.0f / se;
            float se2 = 0.f;
#pragma unroll
            for (int o = 0; o < OO; ++o) se2 += expf(r[o] * inv);
            const float plab = expf(s[labels[gi]] - mx) * inv;
            nll += logf(se2) - plab;
            cnt += 1.f;
        }
    }
    reduce2_part(nll, cnt, qpart + 2 * blockIdx.x);

    // ---- completion counter: last block reduces everything -----------------
    __threadfence();
    __shared__ unsigned ticket;
    if (threadIdx.x == 0) ticket = atomicAdd(cnt_dev, 1u);
    __syncthreads();
    if (ticket == NQBLK - 1) {
        __threadfence();
        __shared__ float s1[256], s2[256], s3[256], s4[256];
        float q1 = 0.f, q2 = 0.f, e1 = 0.f, e2 = 0.f;
        for (int i = threadIdx.x; i < NQBLK; i += 256) {
            q1 += qpart[2 * i]; q2 += qpart[2 * i + 1];
        }
        for (int i = threadIdx.x; i < 196; i += 256) {
            e1 += epart[2 * i]; e2 += epart[2 * i + 1];
        }
        const int t = threadIdx.x;
        s1[t] = q1; s2[t] = q2; s3[t] = e1; s4[t] = e2;
        __syncthreads();
        for (int off = 128; off > 0; off >>= 1) {
            if (t < off) {
                s1[t] += s1[t + off]; s2[t] += s2[t + off];
                s3[t] += s3[t + off]; s4[t] += s4[t + off];
            }
            __syncthreads();
        }
        if (t == 0)
            out[0] = s3[0] / fmaxf(s4[0], 1.0f) + s1[0] / fmaxf(s2[0], 1.0f);
    }
}

extern "C" void kernel_launch(void* const* d_in, const int* in_sizes, int n_in,
                              void* d_out, int out_size, void* d_ws, size_t ws_size,
                              hipStream_t stream) {
    const float* x     = (const float*)d_in[0];
    const int*   jlab  = (const int*)d_in[1];
    const int*   jmask = (const int*)d_in[2];
    const int*   qlab  = (const int*)d_in[3];
    const int*   qmask = (const int*)d_in[4];
    const float* pw    = (const float*)d_in[5];
    const float* pb    = (const float*)d_in[6];
    const float* fw    = (const float*)d_in[7];
    const float* fb    = (const float*)d_in[8];
    const float* vw    = (const float*)d_in[9];
    const float* vb    = (const float*)d_in[10];
    const float* U     = (const float*)d_in[11];

    float* out  = (float*)d_out;
    float* ws   = (float*)d_ws;
    unsigned* cnt_dev = (unsigned*)(ws + WS_CNT);
    float* hp   = ws + WS_HP;
    float* tp   = ws + WS_TP;
    float* val  = ws + WS_VAL;
    float* UT   = ws + WS_UT;
    __hip_bfloat16* vub   = (__hip_bfloat16*)(ws + WS_VUB);
    __hip_bfloat16* pairb = (__hip_bfloat16*)(ws + WS_PAIRB);
    __hip_bfloat16* fwb   = (__hip_bfloat16*)(ws + WS_FWB);
    float* qpart = ws + WS_QPART;
    float* epart = ws + WS_EPART;

    float* joint = out + 1;
    float* qsc   = out + 1 + (long)NPAIR * LL;

    hipMemsetAsync(cnt_dev, 0, sizeof(unsigned), stream);
    k_pre<<<1376, 256, 0, stream>>>(x, pw, vw, vb, U, fw, hp, tp, val, UT, fwb);
    k_mid<<<728, 256, 0, stream>>>(val, UT, vub, hp, tp, pb, pairb);
    k_heavy<<<NHEAVY, 256, 0, stream>>>(pairb, fwb, fb, jlab, jmask, joint, epart, vub, qsc);
    k_qloss<<<NQBLK, 256, 0, stream>>>(qsc, qlab, qmask, qpart, epart, out, cnt_dev);
}

// Round 19
// 182.376 us; speedup vs baseline: 3.7209x; 3.7209x over previous
//
#include <hip/hip_runtime.h>
#include <hip/hip_bf16.h>

#define BB 2
#define SS 112
#define HH 768
#define MM 256
#define LL 54
#define OO 10
#define NPAIR (BB*SS*SS)          // 25088
#define NQPOS (BB*SS*SS*SS)       // 2809856
#define SO (SS*OO)                // 1120
#define SOP 1152                  // padded row count for vU area
#define S2 (SS*SS)                // 12544
#define NQBLK (NQPOS/512)         // 5488
#define NJBLK (NPAIR/128)         // 196 jointg blocks (CE partials)
#define NHEAVY (NJBLK + 9*98*BB)  // 1960

typedef short bf16x8 __attribute__((ext_vector_type(8)));
typedef float f32x4 __attribute__((ext_vector_type(4)));

// workspace layout (float units)
#define WS_HP    64
#define WS_TP    57408
#define WS_VAL   114752
#define WS_UT    172096
#define WS_VUB   827456          // bf16 area: BB*SOP*MM bf16
#define WS_PAIRB 1122368         // bf16 area: NPAIR*MM bf16
#define WS_FWB   4333632         // bf16 area: 64*MM bf16
#define WS_QPART 4341824         // 2*NQBLK floats
#define WS_EPART 4352800         // 2*NJBLK floats

__device__ __forceinline__ float gelu_exact(float v) {
    return 0.5f * v * (1.0f + erff(v * 0.70710678118654752f));
}

// ---- 1. k_pre: proj (672) | transU (640) | prepB (64) ----------------------
__global__ __launch_bounds__(256) void k_pre(const float* __restrict__ x,
                                             const float* __restrict__ pw,
                                             const float* __restrict__ vw,
                                             const float* __restrict__ vb,
                                             const float* __restrict__ U,
                                             const float* __restrict__ fw,
                                             float* __restrict__ hp,
                                             float* __restrict__ tp,
                                             float* __restrict__ val,
                                             float* __restrict__ UT,
                                             __hip_bfloat16* __restrict__ fwb) {
    __shared__ float sm[1056];                  // max(768, 32*33)
    const int id = blockIdx.x;
    const int tid = threadIdx.x;
    if (id < 672) {
        const int row = id % 224, sel = id / 224;
        const float* xr = x + (long)row * HH;
        for (int i = tid; i < HH; i += 256) sm[i] = xr[i];
        __syncthreads();
        const int m = tid;
        const float* w = (sel == 0) ? pw : (sel == 1) ? (pw + (long)HH * MM) : vw;
        float a = 0.f;
        for (int h = 0; h < HH; ++h)
            a = fmaf(sm[h], w[(long)h * MM + m], a);
        if (sel == 0)      hp[(long)row * MM + m] = a;
        else if (sel == 1) tp[(long)row * MM + m] = a;
        else               val[(long)row * MM + m] = gelu_exact(a + vb[m]);
    } else if (id < 1312) {
        const int t = id - 672;
        const int o = t / 64, rest = t % 64;
        const int i0 = (rest >> 3) * 32, j0 = (rest & 7) * 32;
        const int tx = tid & 31, ty = tid >> 5;  // 32 x 8
        float (*tt)[33] = (float(*)[33])sm;
        for (int r = 0; r < 32; r += 8)
            tt[ty + r][tx] = U[((long)(o * MM + i0 + ty + r)) * MM + j0 + tx];
        __syncthreads();
        for (int r = 0; r < 32; r += 8)
            UT[((long)(o * MM + j0 + ty + r)) * MM + i0 + tx] = tt[tx][ty + r];
    } else {
        const int idx2 = (id - 1312) * 256 + tid;   // 0..16383
        const int c = idx2 >> 8, k = idx2 & 255;
        const float v = (c < LL) ? fw[(long)k * LL + c] : 0.f;
        fwb[idx2] = __float2bfloat16(v);
    }
}

// ---- 2. k_mid: vU (280) | pair (448) ---------------------------------------
__global__ __launch_bounds__(256) void k_mid(const float* __restrict__ val,
                                             const float* __restrict__ UT,
                                             __hip_bfloat16* __restrict__ vub,
                                             const float* __restrict__ hp,
                                             const float* __restrict__ tp,
                                             const float* __restrict__ pb,
                                             __hip_bfloat16* __restrict__ pairb) {
    __shared__ float sm[8 * MM];                // 8 KB
    const int id = blockIdx.x;
    const int tid = threadIdx.x;
    if (id < 280) {
        const int b = id / 140, r = id % 140;
        const int o = r / 14, zt = r % 14;
        const int z0 = zt * 8;
        float (*vs)[MM] = (float(*)[MM])sm;
        for (int idx = tid; idx < 8 * MM; idx += 256) {
            const int zz = idx >> 8, m = idx & 255;
            vs[zz][m] = val[((long)(b * SS + z0 + zz)) * MM + m];
        }
        __syncthreads();
        const int i = tid;
        float acc[8];
#pragma unroll
        for (int zz = 0; zz < 8; ++zz) acc[zz] = 0.f;
        const float* utp = UT + (long)o * MM * MM + i;
        for (int j = 0; j < MM; ++j) {
            const float u = utp[(long)j * MM];
#pragma unroll
            for (int zz = 0; zz < 8; ++zz) acc[zz] = fmaf(vs[zz][j], u, acc[zz]);
        }
#pragma unroll
        for (int zz = 0; zz < 8; ++zz)
            vub[((long)b * SOP + (z0 + zz) * OO + o) * MM + i] = __float2bfloat16(acc[zz]);
    } else {
        const int p = id - 280;                 // 0..447
        const int bx = p % 224;
        const int y0base = (p / 224) * 56;
        sm[tid] = hp[(long)bx * MM + tid] + pb[tid];
        __syncthreads();
        const int b = bx / SS;
        const int half = tid >> 7;
        const int m0 = (tid & 127) * 2;
        const float h0 = sm[m0], h1 = sm[m0 + 1];
        for (int y0 = y0base; y0 < y0base + 56; y0 += 2) {
            const int y = y0 + half;
            const float2 t2 = *(const float2*)(tp + ((long)(b * SS + y)) * MM + m0);
            __hip_bfloat162 o2;
            o2.x = __float2bfloat16(gelu_exact(h0 + t2.x));
            o2.y = __float2bfloat16(gelu_exact(h1 + t2.y));
            *(__hip_bfloat162*)(pairb + ((long)bx * SS + y) * MM + m0) = o2;
        }
    }
}

// ---- block reduce -> per-block partial (no atomics) ------------------------
__device__ __forceinline__ void reduce2_part(float v1, float v2, float* slot) {
    const int lane = threadIdx.x & 63, wid = threadIdx.x >> 6;
#pragma unroll
    for (int off = 32; off > 0; off >>= 1) {
        v1 += __shfl_down(v1, off, 64);
        v2 += __shfl_down(v2, off, 64);
    }
    __shared__ float w1[4], w2[4];
    if (lane == 0) { w1[wid] = v1; w2[wid] = v2; }
    __syncthreads();
    if (threadIdx.x == 0) {
        slot[0] = w1[0] + w1[1] + w1[2] + w1[3];
        slot[1] = w2[0] + w2[1] + w2[2] + w2[3];
    }
}

// ---- 3. k_heavy: jointg+CE (196) | qgemm (1764) ----------------------------
__global__ __launch_bounds__(256) void k_heavy(const __hip_bfloat16* __restrict__ pairb,
                                               const __hip_bfloat16* __restrict__ fwb,
                                               const float* __restrict__ fb,
                                               const int* __restrict__ jlab,
                                               const int* __restrict__ jmask,
                                               float* __restrict__ joint,
                                               float* __restrict__ epart,
                                               const __hip_bfloat16* __restrict__ vub,
                                               float* __restrict__ qout) {
    __shared__ __align__(16) char smem[32768];
    char* Al = smem;
    const int id = blockIdx.x;
    const int tid = threadIdx.x;
    const int lane = tid & 63, wid = tid >> 6;
    const int rl = lane & 15, kb = lane >> 4;

    if (id < NJBLK) {
        // ================= jointg + element-CE =================
        char* Bl = smem + 16384;                // B tile 64x64
        const int r0 = id * 128;

        int arow[4], aci[4], wadA[4];
#pragma unroll
        for (int j = 0; j < 4; ++j) {
            const int chunk = tid + 256 * j;
            arow[j] = chunk >> 3; aci[j] = chunk & 7;
            wadA[j] = (arow[j] * 128 + aci[j] * 16) ^ ((arow[j] & 7) << 4);
        }
        int brow[2], bci[2], wadB[2];
#pragma unroll
        for (int j = 0; j < 2; ++j) {
            const int chunk = tid + 256 * j;
            brow[j] = chunk >> 3; bci[j] = chunk & 7;
            wadB[j] = (brow[j] * 128 + bci[j] * 16) ^ ((brow[j] & 7) << 4);
        }

        f32x4 acc[2][4] = {};
        float4 ra[4], rb[2];

        auto issue = [&](int kt) {
#pragma unroll
            for (int j = 0; j < 4; ++j)
                ra[j] = *(const float4*)((const char*)pairb +
                         ((long)(r0 + arow[j]) * MM + kt * 64 + aci[j] * 8) * 2);
#pragma unroll
            for (int j = 0; j < 2; ++j)
                rb[j] = *(const float4*)((const char*)fwb +
                         ((long)brow[j] * MM + kt * 64 + bci[j] * 8) * 2);
        };
        auto dowrite = [&]() {
#pragma unroll
            for (int j = 0; j < 4; ++j) *(float4*)(Al + wadA[j]) = ra[j];
#pragma unroll
            for (int j = 0; j < 2; ++j) *(float4*)(Bl + wadB[j]) = rb[j];
        };
        auto compute = [&]() {
#pragma unroll
            for (int ks = 0; ks < 2; ++ks) {
                bf16x8 af[2], bv[4];
#pragma unroll
                for (int m = 0; m < 2; ++m) {
                    const int rr = wid * 32 + m * 16 + rl;
                    af[m] = *(const bf16x8*)(Al + ((rr * 128 + ks * 64 + kb * 16) ^ ((rr & 7) << 4)));
                }
#pragma unroll
                for (int n = 0; n < 4; ++n) {
                    const int cc = n * 16 + rl;
                    bv[n] = *(const bf16x8*)(Bl + ((cc * 128 + ks * 64 + kb * 16) ^ ((cc & 7) << 4)));
                }
#pragma unroll
                for (int m = 0; m < 2; ++m)
#pragma unroll
                    for (int n = 0; n < 4; ++n)
                        acc[m][n] = __builtin_amdgcn_mfma_f32_16x16x32_bf16(af[m], bv[n], acc[m][n], 0, 0, 0);
            }
        };

        issue(0); dowrite(); __syncthreads();
        for (int kt = 0; kt < 4; ++kt) {
            if (kt < 3) issue(kt + 1);
            compute();
            __syncthreads();
            if (kt < 3) { dowrite(); __syncthreads(); }
        }

        // epilogue: write joint + stage (with bias) to LDS (stride 55) for CE
        float* stage = (float*)smem;
        __syncthreads();
#pragma unroll
        for (int m = 0; m < 2; ++m)
#pragma unroll
            for (int n = 0; n < 4; ++n) {
                const int col = n * 16 + rl;
                if (col < LL) {
                    const float bias = fb[col];
                    const int lrow0 = wid * 32 + m * 16 + kb * 4;
#pragma unroll
                    for (int j = 0; j < 4; ++j) {
                        const float v = acc[m][n][j] + bias;
                        joint[(long)(r0 + lrow0 + j) * LL + col] = v;
                        stage[(lrow0 + j) * 55 + col] = v;
                    }
                }
            }
        __syncthreads();

        float nll = 0.f, cnt = 0.f;
        if (tid < 128) {
            const int gi = r0 + tid;
            if (jmask[gi] != 0) {
                const float* s = stage + tid * 55;
                float mx = -3.4e38f;
                for (int l = 0; l < LL; ++l) mx = fmaxf(mx, s[l]);
                float se = 0.f;
                for (int l = 0; l < LL; ++l) se += expf(s[l] - mx);
                nll = mx + logf(se) - s[jlab[gi]];
                cnt = 1.f;
            }
        }
        reduce2_part(nll, cnt, epart + 2 * id);
    } else {
        // ================= q_score GEMM 128x128 =================
        char* Bl = smem + 16384;
        const int qid = id - NJBLK;
        const int c0 = (qid % 9) * 128;
        const int r0 = ((qid / 9) % 98) * 128;
        const int b = qid / (9 * 98);
        const __hip_bfloat16* A  = pairb + (long)b * S2 * MM;
        const __hip_bfloat16* Bm = vub + (long)b * SOP * MM;
        const int wr = wid >> 1, wc = wid & 1;

        int arow[4], aci[4], wad[4];
#pragma unroll
        for (int j = 0; j < 4; ++j) {
            const int chunk = tid + 256 * j;
            arow[j] = chunk >> 3; aci[j] = chunk & 7;
            wad[j] = (arow[j] * 128 + aci[j] * 16) ^ ((arow[j] & 7) << 4);
        }

        f32x4 acc[4][4] = {};
        float4 ra[4], rb[4];

        auto issue = [&](int kt) {
#pragma unroll
            for (int j = 0; j < 4; ++j) {
                ra[j] = *(const float4*)((const char*)A +
                         ((long)(r0 + arow[j]) * MM + kt * 64 + aci[j] * 8) * 2);
                rb[j] = *(const float4*)((const char*)Bm +
                         ((long)(c0 + arow[j]) * MM + kt * 64 + aci[j] * 8) * 2);
            }
        };
        auto dowrite = [&]() {
#pragma unroll
            for (int j = 0; j < 4; ++j) {
                *(float4*)(Al + wad[j]) = ra[j];
                *(float4*)(Bl + wad[j]) = rb[j];
            }
        };
        auto compute = [&]() {
#pragma unroll
            for (int ks = 0; ks < 2; ++ks) {
                bf16x8 af[4], bv[4];
#pragma unroll
                for (int m = 0; m < 4; ++m) {
                    const int rr = wr * 64 + m * 16 + rl;
                    af[m] = *(const bf16x8*)(Al + ((rr * 128 + ks * 64 + kb * 16) ^ ((rr & 7) << 4)));
                }
#pragma unroll
                for (int n = 0; n < 4; ++n) {
                    const int cc = wc * 64 + n * 16 + rl;
                    bv[n] = *(const bf16x8*)(Bl + ((cc * 128 + ks * 64 + kb * 16) ^ ((cc & 7) << 4)));
                }
#pragma unroll
                for (int m = 0; m < 4; ++m)
#pragma unroll
                    for (int n = 0; n < 4; ++n)
                        acc[m][n] = __builtin_amdgcn_mfma_f32_16x16x32_bf16(af[m], bv[n], acc[m][n], 0, 0, 0);
            }
        };

        issue(0); dowrite(); __syncthreads();
        for (int kt = 0; kt < 4; ++kt) {
            if (kt < 3) issue(kt + 1);
            compute();
            __syncthreads();
            if (kt < 3) { dowrite(); __syncthreads(); }
        }

        float* C = qout + (long)b * S2 * SO;
#pragma unroll
        for (int m = 0; m < 4; ++m)
#pragma unroll
            for (int n = 0; n < 4; ++n) {
                const int col = c0 + wc * 64 + n * 16 + rl;
                if (col < SO) {
                    const int rbase = r0 + wr * 64 + m * 16 + kb * 4;
#pragma unroll
                    for (int j = 0; j < 4; ++j)
                        C[(long)(rbase + j) * SO + col] = acc[m][n][j];
                }
            }
    }
}

// ---- 4. q loss (LDS-staged, pad-11, partials; NO atomics/fences) -----------
__global__ __launch_bounds__(256) void k_qloss(const float* __restrict__ q,
                                               const int* __restrict__ labels,
                                               const int* __restrict__ mask,
                                               float* __restrict__ qpart) {
    __shared__ float qs[512 * 11];             // 22528 B, stride-11 pad
    const int base = blockIdx.x * 512;
    const float* src = q + (long)base * OO;
    for (int i = threadIdx.x; i < 512 * OO; i += 256) {
        const int p = i / 10, o = i - p * 10;
        qs[p * 11 + o] = src[i];
    }
    __syncthreads();
    float nll = 0.f, cnt = 0.f;
#pragma unroll
    for (int j = 0; j < 2; ++j) {
        const int p = threadIdx.x + 256 * j;
        const int gi = base + p;
        if (mask[gi] != 0) {
            const float* s = qs + p * 11;
            float r[OO];
#pragma unroll
            for (int o = 0; o < OO; ++o) r[o] = s[o];
            float mx = r[0];
#pragma unroll
            for (int o = 1; o < OO; ++o) mx = fmaxf(mx, r[o]);
            float se = 0.f;
#pragma unroll
            for (int o = 0; o < OO; ++o) { r[o] = expf(r[o] - mx); se += r[o]; }
            const float inv = 1.0f / se;
            float se2 = 0.f;
#pragma unroll
            for (int o = 0; o < OO; ++o) se2 += expf(r[o] * inv);
            const float plab = expf(s[labels[gi]] - mx) * inv;
            nll += logf(se2) - plab;
            cnt += 1.f;
        }
    }
    reduce2_part(nll, cnt, qpart + 2 * blockIdx.x);
}

// ---- 5. finalize: reduce partials ------------------------------------------
__global__ __launch_bounds__(256) void k_final(const float* __restrict__ qpart,
                                               const float* __restrict__ epart,
                                               float* __restrict__ out) {
    __shared__ float s1[256], s2[256], s3[256], s4[256];
    float q1 = 0.f, q2 = 0.f, e1 = 0.f, e2 = 0.f;
    for (int i = threadIdx.x; i < NQBLK; i += 256) {
        q1 += qpart[2 * i]; q2 += qpart[2 * i + 1];
    }
    for (int i = threadIdx.x; i < NJBLK; i += 256) {
        e1 += epart[2 * i]; e2 += epart[2 * i + 1];
    }
    const int t = threadIdx.x;
    s1[t] = q1; s2[t] = q2; s3[t] = e1; s4[t] = e2;
    __syncthreads();
    for (int off = 128; off > 0; off >>= 1) {
        if (t < off) {
            s1[t] += s1[t + off]; s2[t] += s2[t + off];
            s3[t] += s3[t + off]; s4[t] += s4[t + off];
        }
        __syncthreads();
    }
    if (t == 0)
        out[0] = s3[0] / fmaxf(s4[0], 1.0f) + s1[0] / fmaxf(s2[0], 1.0f);
}

extern "C" void kernel_launch(void* const* d_in, const int* in_sizes, int n_in,
                              void* d_out, int out_size, void* d_ws, size_t ws_size,
                              hipStream_t stream) {
    const float* x     = (const float*)d_in[0];
    const int*   jlab  = (const int*)d_in[1];
    const int*   jmask = (const int*)d_in[2];
    const int*   qlab  = (const int*)d_in[3];
    const int*   qmask = (const int*)d_in[4];
    const float* pw    = (const float*)d_in[5];
    const float* pb    = (const float*)d_in[6];
    const float* fw    = (const float*)d_in[7];
    const float* fb    = (const float*)d_in[8];
    const float* vw    = (const float*)d_in[9];
    const float* vb    = (const float*)d_in[10];
    const float* U     = (const float*)d_in[11];

    float* out  = (float*)d_out;
    float* ws   = (float*)d_ws;
    float* hp   = ws + WS_HP;
    float* tp   = ws + WS_TP;
    float* val  = ws + WS_VAL;
    float* UT   = ws + WS_UT;
    __hip_bfloat16* vub   = (__hip_bfloat16*)(ws + WS_VUB);
    __hip_bfloat16* pairb = (__hip_bfloat16*)(ws + WS_PAIRB);
    __hip_bfloat16* fwb   = (__hip_bfloat16*)(ws + WS_FWB);
    float* qpart = ws + WS_QPART;
    float* epart = ws + WS_EPART;

    float* joint = out + 1;
    float* qsc   = out + 1 + (long)NPAIR * LL;

    k_pre<<<1376, 256, 0, stream>>>(x, pw, vw, vb, U, fw, hp, tp, val, UT, fwb);
    k_mid<<<728, 256, 0, stream>>>(val, UT, vub, hp, tp, pb, pairb);
    k_heavy<<<NHEAVY, 256, 0, stream>>>(pairb, fwb, fb, jlab, jmask, joint, epart, vub, qsc);
    k_qloss<<<NQBLK, 256, 0, stream>>>(qsc, qlab, qmask, qpart);
    k_final<<<1, 256, 0, stream>>>(qpart, epart, out);
}